// Round 11
// baseline (1102.911 us; speedup 1.0000x reference)
//
#include <hip/hip_runtime.h>
#include <hip/hip_bf16.h>

#define TT 12
#define HDIM 128
#define ODIM 12
#define KS0 136        // LDS h-row stride in shorts (272 B) — l0 only
#define TPAD 36        // fp32 GCN gemm LDS pad

typedef short bf16x8 __attribute__((ext_vector_type(8)));
typedef float f32x16 __attribute__((ext_vector_type(16)));
typedef float f32x4  __attribute__((ext_vector_type(4)));

__device__ __forceinline__ float fastrcp(float x) { return __builtin_amdgcn_rcpf(x); }
__device__ __forceinline__ float sigf(float x) { return fastrcp(1.f + __expf(-x)); }
__device__ __forceinline__ float tanh_fast(float x) { return 1.f - 2.f * fastrcp(1.f + __expf(2.f * x)); }
__device__ __forceinline__ unsigned short f2bf(float f) {
    union { float f; unsigned int u; } v; v.f = f;
    unsigned int r = v.u + 0x7FFFu + ((v.u >> 16) & 1u);
    return (unsigned short)(r >> 16);
}

// ---------------- weight pre-pack (unchanged from R10) ----------------
// mat0 (Whh0): 32x32-frag layout, slots 0..127 at offset 0 (for l0)
// mat1 (Wih1) at +65536, mat2 (Whh1) at +131072: 16x16-frag layout
__global__ void pack_kernel(const float* __restrict__ Whh0, const float* __restrict__ Wih1,
                            const float* __restrict__ Whh1, unsigned short* __restrict__ Wpk)
{
    int idx = blockIdx.x * 256 + threadIdx.x;
    if (idx >= 384 * 64) return;
    int lane = idx & 63;
    int slot = idx >> 6;
    int mat = slot >> 7;
    int rem = slot & 127;
    if (mat == 0) {
        int cb = rem >> 3, s = rem & 7;
        int col = cb * 32 + (lane & 31);
#pragma unroll
        for (int j = 0; j < 8; ++j) {
            int k = s * 16 + ((lane >> 5) << 3) + j;
            Wpk[((size_t)(slot * 64 + lane) << 3) + j] = f2bf(Whh0[col * 128 + k]);
        }
    } else {
        const float* src = (mat == 1) ? Wih1 : Whh1;
        int ct = rem >> 2, ks = rem & 3;
        int col = ct * 16 + (lane & 15);
#pragma unroll
        for (int j = 0; j < 8; ++j) {
            int k = ks * 32 + ((lane >> 4) << 3) + j;
            Wpk[((size_t)(slot * 64 + lane) << 3) + j] = f2bf(src[col * 128 + k]);
        }
    }
}

// ---------------- L0: layer-0 LSTM, Whh0 resident in LDS (unchanged; ~264 us) ----------------
__global__ __launch_bounds__(512, 1) void lstm_l0_kernel(
    const float* __restrict__ x,
    const unsigned short* __restrict__ Wpk,
    const float* __restrict__ Wih0,
    const float* __restrict__ bih0, const float* __restrict__ bhh0,
    unsigned short* __restrict__ h0seq,       // [N][12][128] bf16
    int N, int ntiles)
{
    __shared__ unsigned short wlds[65536];
    __shared__ unsigned short hA0[64 * KS0];
    __shared__ float xls[64 * 24];

    const int tid  = threadIdx.x;
    const int w    = tid >> 6;
    const int ln   = tid & 63;
    const int ln31 = ln & 31;
    const int half = ln >> 5;
    const int wsub = w & 3;
    const int rb   = w >> 2;
    const int col  = wsub * 32 + ln31;

    for (int i = tid * 8; i < 65536; i += 512 * 8)
        *(bf16x8*)(wlds + i) = *(const bf16x8*)(Wpk + i);

    float wx0[4], wx1[4], br0[4];
#pragma unroll
    for (int g = 0; g < 4; ++g) {
        int row = (g << 7) + col;
        wx0[g] = Wih0[row * 2 + 0];
        wx1[g] = Wih0[row * 2 + 1];
        br0[g] = bih0[row] + bhh0[row];
    }

    for (int tile = blockIdx.x; tile < ntiles; tile += gridDim.x) {
        const int nbase = tile * 64;
        __syncthreads();
        for (int i = tid; i < 64 * 24; i += 512) {
            int n = nbase + i / 24;
            xls[i] = (n < N) ? x[nbase * 24 + i] : 0.f;
        }
        for (int i = tid; i < 64 * KS0; i += 512) hA0[i] = 0;
        float c0[16];
#pragma unroll
        for (int r = 0; r < 16; ++r) c0[r] = 0.f;
        __syncthreads();

        for (int t = 0; t < TT; ++t) {
            f32x16 acc[4];
#pragma unroll
            for (int g = 0; g < 4; ++g)
#pragma unroll
                for (int e = 0; e < 16; ++e) acc[g][e] = 0.f;
#pragma unroll
            for (int s = 0; s < 8; ++s) {
                bf16x8 a = *(const bf16x8*)(hA0 + (rb * 32 + ln31) * KS0 + s * 16 + half * 8);
#pragma unroll
                for (int g = 0; g < 4; ++g) {
                    int cb = g * 4 + wsub;
                    bf16x8 b = *(const bf16x8*)(wlds + (((cb * 8 + s) * 64 + ln) << 3));
                    acc[g] = __builtin_amdgcn_mfma_f32_32x32x16_bf16(a, b, acc[g], 0, 0, 0);
                }
            }
            __syncthreads();                   // B1
#pragma unroll
            for (int r = 0; r < 16; ++r) {
                int node = rb * 32 + (r & 3) + 8 * (r >> 2) + 4 * half;
                float xa = xls[node * 24 + t * 2 + 0];
                float xb = xls[node * 24 + t * 2 + 1];
                float zi = acc[0][r] + br0[0] + wx0[0] * xa + wx1[0] * xb;
                float zf = acc[1][r] + br0[1] + wx0[1] * xa + wx1[1] * xb;
                float zg = acc[2][r] + br0[2] + wx0[2] * xa + wx1[2] * xb;
                float zo = acc[3][r] + br0[3] + wx0[3] * xa + wx1[3] * xb;
                float cn = sigf(zf) * c0[r] + sigf(zi) * tanh_fast(zg);
                c0[r] = cn;
                float h = sigf(zo) * tanh_fast(cn);
                unsigned short us = f2bf(h);
                hA0[node * KS0 + col] = us;
                int n = nbase + node;
                if (n < N) h0seq[(n * TT + t) * HDIM + col] = us;
            }
            __syncthreads();                   // B2
        }
    }
}

// ---------------- L1: 16x16x32, double-buffered frag-contiguous hA1, 1 barrier/t ----------------
// hA1 element (m,ch): addr = ((rt*4+ks)*64 + q*16 + l15)*8 + j, m=rt*16+l15, ch=ks*32+q*8+j.
// GEMM A-read for lane ln: ((rt*4+ks)*64 + ln)*8 -> lane-contiguous ds_read_b128 (0 conflicts).
__global__ __launch_bounds__(512) void lstm_l1f_kernel(
    const unsigned short* __restrict__ h0seq, // [N][12][128] bf16
    const unsigned short* __restrict__ Wpk,   // +65536 = Wih1(16), +131072 = Whh1(16)
    const float* __restrict__ bih1, const float* __restrict__ bhh1,
    float* __restrict__ hbuf,                 // [N][128] fp32 out
    int N, int ntiles)
{
    __shared__ unsigned short wlds[65536];    // Whh1, 128 KB
    __shared__ unsigned short hA1[2][8192];   // 2 x 16 KB (total LDS = 160 KB exactly)

    const int tid  = threadIdx.x;
    const int w    = tid >> 6;                // 0..7: ch block
    const int ln   = tid & 63;
    const int l15  = ln & 15;
    const int quad = ln >> 4;
    const int ch   = w * 16 + l15;
    const int chk  = ch >> 5;                 // ks' of this thread's channel
    const int chq  = (ch >> 3) & 3;           // q'
    const int chj  = ch & 7;                  // j'

    for (int i = tid * 8; i < 65536; i += 512 * 8)
        *(bf16x8*)(wlds + i) = *(const bf16x8*)(Wpk + 131072 + i);

    // Wih1 fragments -> registers (16 frags = 64 VGPR)
    bf16x8 wfr[4][4];
#pragma unroll
    for (int g = 0; g < 4; ++g)
#pragma unroll
        for (int ks = 0; ks < 4; ++ks) {
            int slot = (g * 8 + w) * 4 + ks;
            wfr[g][ks] = *(const bf16x8*)(Wpk + 65536 + ((size_t)(slot * 64 + ln) << 3));
        }

    float br1[4];
#pragma unroll
    for (int g = 0; g < 4; ++g) {
        int row = (g << 7) + ch;
        br1[g] = bih1[row] + bhh1[row];
    }

    const bf16x8 zv = {0, 0, 0, 0, 0, 0, 0, 0};
    __syncthreads();

    for (int tile = blockIdx.x; tile < ntiles; tile += gridDim.x) {
        __syncthreads();                       // prev tile's buf0 reads done
        for (int i = tid; i < 1024; i += 512)  // zero buf0 (t=0 reads it)
            *(bf16x8*)(hA1[0] + i * 8) = zv;
        float c1[16];
#pragma unroll
        for (int r = 0; r < 16; ++r) c1[r] = 0.f;

        // A-row ids for this lane's 4 row-tiles
        int na[4]; bool ok[4];
#pragma unroll
        for (int rt = 0; rt < 4; ++rt) { na[rt] = tile * 64 + rt * 16 + l15; ok[rt] = na[rt] < N; }

        // preload h0 frags for t=0 (both halves)
        bf16x8 aA[8], aB[8];
#pragma unroll
        for (int ks = 0; ks < 2; ++ks)
#pragma unroll
            for (int rt = 0; rt < 4; ++rt)
                aA[ks * 4 + rt] = ok[rt] ? __builtin_nontemporal_load(
                    (const bf16x8*)(h0seq + ((size_t)na[rt] * TT + 0) * HDIM + ks * 32 + quad * 8)) : zv;
#pragma unroll
        for (int ks = 0; ks < 2; ++ks)
#pragma unroll
            for (int rt = 0; rt < 4; ++rt)
                aB[ks * 4 + rt] = ok[rt] ? __builtin_nontemporal_load(
                    (const bf16x8*)(h0seq + ((size_t)na[rt] * TT + 0) * HDIM + (ks + 2) * 32 + quad * 8)) : zv;
        __syncthreads();                       // buf0 zero visible

        for (int t = 0; t < TT; ++t) {
            const unsigned short* usp = hA1[t & 1];
            unsigned short* dst = hA1[(t & 1) ^ 1];
            const bool pf = (t + 1 < TT);

            f32x4 acc[4][4];
#pragma unroll
            for (int rt = 0; rt < 4; ++rt)
#pragma unroll
                for (int g = 0; g < 4; ++g)
#pragma unroll
                    for (int e = 0; e < 4; ++e) acc[rt][g][e] = 0.f;

            // input GEMM ks 0..1 (consume aA), then prefetch aA for t+1
#pragma unroll
            for (int ks = 0; ks < 2; ++ks)
#pragma unroll
                for (int g = 0; g < 4; ++g)
#pragma unroll
                    for (int rt = 0; rt < 4; ++rt)
                        acc[rt][g] = __builtin_amdgcn_mfma_f32_16x16x32_bf16(aA[ks * 4 + rt], wfr[g][ks], acc[rt][g], 0, 0, 0);
#pragma unroll
            for (int ks = 0; ks < 2; ++ks)
#pragma unroll
                for (int rt = 0; rt < 4; ++rt)
                    aA[ks * 4 + rt] = (pf && ok[rt]) ? __builtin_nontemporal_load(
                        (const bf16x8*)(h0seq + ((size_t)na[rt] * TT + t + 1) * HDIM + ks * 32 + quad * 8)) : aA[ks * 4 + rt];

            // input GEMM ks 2..3 (consume aB), then prefetch aB for t+1
#pragma unroll
            for (int ks = 0; ks < 2; ++ks)
#pragma unroll
                for (int g = 0; g < 4; ++g)
#pragma unroll
                    for (int rt = 0; rt < 4; ++rt)
                        acc[rt][g] = __builtin_amdgcn_mfma_f32_16x16x32_bf16(aB[ks * 4 + rt], wfr[g][ks + 2], acc[rt][g], 0, 0, 0);
#pragma unroll
            for (int ks = 0; ks < 2; ++ks)
#pragma unroll
                for (int rt = 0; rt < 4; ++rt)
                    aB[ks * 4 + rt] = (pf && ok[rt]) ? __builtin_nontemporal_load(
                        (const bf16x8*)(h0seq + ((size_t)na[rt] * TT + t + 1) * HDIM + (ks + 2) * 32 + quad * 8)) : aB[ks * 4 + rt];

            // recurrent GEMM from usp (lane-contiguous reads) + wlds
#pragma unroll
            for (int ks = 0; ks < 4; ++ks) {
                bf16x8 a[4];
#pragma unroll
                for (int rt = 0; rt < 4; ++rt)
                    a[rt] = *(const bf16x8*)(usp + (((rt * 4 + ks) * 64 + ln) << 3));
#pragma unroll
                for (int g = 0; g < 4; ++g) {
                    int slot = (g * 8 + w) * 4 + ks;
                    bf16x8 b = *(const bf16x8*)(wlds + ((size_t)(slot * 64 + ln) << 3));
#pragma unroll
                    for (int rt = 0; rt < 4; ++rt)
                        acc[rt][g] = __builtin_amdgcn_mfma_f32_16x16x32_bf16(a[rt], b, acc[rt][g], 0, 0, 0);
                }
            }

            // epilogue -> dst (other buffer; no read conflict, no pre-barrier needed)
#pragma unroll
            for (int rt = 0; rt < 4; ++rt) {
#pragma unroll
                for (int rg = 0; rg < 4; ++rg) {
                    int ci = rt * 4 + rg;
                    float zi = acc[rt][0][rg] + br1[0];
                    float zf = acc[rt][1][rg] + br1[1];
                    float zg = acc[rt][2][rg] + br1[2];
                    float zo = acc[rt][3][rg] + br1[3];
                    float cn = sigf(zf) * c1[ci] + sigf(zi) * tanh_fast(zg);
                    c1[ci] = cn;
                    float h = sigf(zo) * tanh_fast(cn);
                    if (t + 1 < TT) {
                        dst[(((rt * 4 + chk) * 64 + chq * 16 + quad * 4 + rg) << 3) + chj] = f2bf(h);
                    } else {
                        int n = tile * 64 + rt * 16 + quad * 4 + rg;
                        if (n < N) hbuf[n * HDIM + ch] = h;
                    }
                }
            }
            __syncthreads();                   // single barrier: dst complete, usp reads done
        }
    }
}

// ---------------- GCN: CSR build (unchanged) ----------------
__global__ void deg_count_kernel(const int* __restrict__ ei, int* __restrict__ degi, int E)
{
    int e = blockIdx.x * 256 + threadIdx.x;
    if (e < E) atomicAdd(&degi[ei[E + e]], 1);
}

__global__ void row_alloc_kernel(const int* __restrict__ degi, int* __restrict__ row_ptr,
                                 float* __restrict__ dinv, int* __restrict__ counter, int N)
{
    int n = blockIdx.x * 256 + threadIdx.x;
    int lane = threadIdx.x & 63;
    int v = (n < N) ? degi[n] : 0;
    int incl = v;
    for (int off = 1; off < 64; off <<= 1) {
        int u = __shfl_up(incl, off);
        if (lane >= off) incl += u;
    }
    int base = 0;
    if (lane == 63) base = atomicAdd(counter, incl);
    base = __shfl(base, 63);
    if (n < N) {
        row_ptr[n] = base + (incl - v);
        dinv[n] = rsqrtf((float)(v + 1));
    }
}

__global__ void csr_fill_kernel(const int* __restrict__ ei, const int* __restrict__ row_ptr,
                                int* __restrict__ fill, int* __restrict__ csr_src, int E)
{
    int e = blockIdx.x * 256 + threadIdx.x;
    if (e < E) {
        int d = ei[E + e];
        int p = atomicAdd(&fill[d], 1);
        csr_src[row_ptr[d] + p] = ei[e];
    }
}

// ---------------- GCN: transform + aggregate (fp16 messages; unchanged) ----------------
__global__ __launch_bounds__(256) void gemm128_kernel(const float* __restrict__ X,
                                                      const float* __restrict__ W,
                                                      _Float16* __restrict__ Y, int N)
{
    __shared__ float XT[128 * TPAD];
    const int tid = threadIdx.x;
    const int nbase = blockIdx.x * 32;
    for (int idx = tid; idx < 32 * 128; idx += 256) {
        int m = idx >> 7, k = idx & 127;
        int n = nbase + m;
        XT[k * TPAD + m] = (n < N) ? X[n * HDIM + k] : 0.f;
    }
    __syncthreads();
    const int c  = tid & 63;
    const int mb = (tid >> 6) << 3;
    float acc[8][2];
#pragma unroll
    for (int i = 0; i < 8; ++i) { acc[i][0] = 0.f; acc[i][1] = 0.f; }
    for (int k = 0; k < 128; ++k) {
        const float* xr = &XT[k * TPAD + mb];
        float4 a0 = *(const float4*)(xr);
        float4 a1 = *(const float4*)(xr + 4);
        float a[8] = {a0.x, a0.y, a0.z, a0.w, a1.x, a1.y, a1.z, a1.w};
        float b0 = W[k * HDIM + c];
        float b1 = W[k * HDIM + c + 64];
#pragma unroll
        for (int i = 0; i < 8; ++i) {
            acc[i][0] = fmaf(a[i], b0, acc[i][0]);
            acc[i][1] = fmaf(a[i], b1, acc[i][1]);
        }
    }
#pragma unroll
    for (int i = 0; i < 8; ++i) {
        int n = nbase + mb + i;
        if (n < N) {
            Y[n * HDIM + c]      = (_Float16)acc[i][0];
            Y[n * HDIM + c + 64] = (_Float16)acc[i][1];
        }
    }
}

__global__ void gemm12_kernel(const float* __restrict__ X, const float* __restrict__ W2,
                              _Float16* __restrict__ Y, int N)
{
    int idx = blockIdx.x * 256 + threadIdx.x;
    int n = idx / ODIM, c = idx - n * ODIM;
    if (n >= N) return;
    float acc = 0.f;
    for (int k = 0; k < 128; ++k) acc = fmaf(X[n * HDIM + k], W2[k * ODIM + c], acc);
    Y[n * ODIM + c] = (_Float16)acc;
}

__global__ __launch_bounds__(128) void agg128_kernel(const _Float16* __restrict__ hW,
        const int* __restrict__ row_ptr, const int* __restrict__ degi,
        const int* __restrict__ csr_src, const float* __restrict__ dinv,
        const float* __restrict__ bias, float* __restrict__ out, int N, int do_relu)
{
    int n = blockIdx.x;
    int c = threadIdx.x;
    float dn = dinv[n];
    float acc = (float)hW[n * HDIM + c] * dn * dn;
    int start = row_ptr[n];
    int cnt = degi[n];
    for (int i = 0; i < cnt; ++i) {
        int s = csr_src[start + i];
        acc = fmaf((float)hW[s * HDIM + c], dinv[s] * dn, acc);
    }
    float v = acc + bias[c];
    if (do_relu) v = fmaxf(v, 0.f);
    out[n * HDIM + c] = v;
}

__global__ void agg12_kernel(const _Float16* __restrict__ hW, const int* __restrict__ row_ptr,
        const int* __restrict__ degi, const int* __restrict__ csr_src,
        const float* __restrict__ dinv, const float* __restrict__ b2,
        float* __restrict__ out, int N)
{
    int idx = blockIdx.x * 256 + threadIdx.x;
    int n = idx / ODIM, c = idx - n * ODIM;
    if (n >= N) return;
    float dn = dinv[n];
    float acc = (float)hW[n * ODIM + c] * dn * dn;
    int start = row_ptr[n], cnt = degi[n];
    for (int i = 0; i < cnt; ++i) {
        int s = csr_src[start + i];
        acc = fmaf((float)hW[s * ODIM + c], dinv[s] * dn, acc);
    }
    out[n * ODIM + c] = acc + b2[c];
}

extern "C" void kernel_launch(void* const* d_in, const int* in_sizes, int n_in,
                              void* d_out, int out_size, void* d_ws, size_t ws_size,
                              hipStream_t stream)
{
    const float* x     = (const float*)d_in[0];
    const int*   ei    = (const int*)d_in[1];
    const float* Wih0  = (const float*)d_in[2];
    const float* Whh0  = (const float*)d_in[3];
    const float* bih0  = (const float*)d_in[4];
    const float* bhh0  = (const float*)d_in[5];
    const float* Wih1  = (const float*)d_in[6];
    const float* Whh1  = (const float*)d_in[7];
    const float* bih1  = (const float*)d_in[8];
    const float* bhh1  = (const float*)d_in[9];
    const float* W0    = (const float*)d_in[10];
    const float* b0    = (const float*)d_in[11];
    const float* W1    = (const float*)d_in[12];
    const float* b1    = (const float*)d_in[13];
    const float* W2    = (const float*)d_in[14];
    const float* b2    = (const float*)d_in[15];
    float* out = (float*)d_out;

    const int N = in_sizes[0] / (TT * 2);
    const int E = in_sizes[1] / 2;

    // ---- workspace layout ----
    unsigned short* Wpk = (unsigned short*)d_ws;          // 384 KB
    float* fbase = (float*)((char*)d_ws + 393216);
    float* hbuf = fbase;                                  // N*128 fp32
    float* buf1 = hbuf + (size_t)N * HDIM;                // N*128 (fp16 messages)
    float* buf2 = buf1 + (size_t)N * HDIM;                // N*128 fp32
    float* dinv = buf2 + (size_t)N * HDIM;                // N
    int* degi    = (int*)(dinv + N);                      // N
    int* fill    = degi + N;                              // N
    int* counter = fill + N;                              // 1
    int* row_ptr = counter + 1;                           // N
    int* csr_src = row_ptr + N;                           // E
    size_t h0_off = (((size_t)((char*)(csr_src + E) - (char*)d_ws)) + 255) & ~(size_t)255;
    unsigned short* h0seq = (unsigned short*)((char*)d_ws + h0_off);   // N*12*128 bf16
    _Float16* buf1h = (_Float16*)buf1;

    hipMemsetAsync(degi, 0, (size_t)(2 * N + 1) * sizeof(int), stream);

    pack_kernel<<<(384 * 64 + 255) / 256, 256, 0, stream>>>(Whh0, Wih1, Whh1, Wpk);

    const int ntiles = (N + 63) / 64;
    lstm_l0_kernel<<<256, 512, 0, stream>>>(x, Wpk, Wih0, bih0, bhh0, h0seq, N, ntiles);
    lstm_l1f_kernel<<<256, 512, 0, stream>>>(h0seq, Wpk, bih1, bhh1, hbuf, N, ntiles);

    deg_count_kernel<<<(E + 255) / 256, 256, 0, stream>>>(ei, degi, E);
    row_alloc_kernel<<<(N + 255) / 256, 256, 0, stream>>>(degi, row_ptr, dinv, counter, N);
    csr_fill_kernel<<<(E + 255) / 256, 256, 0, stream>>>(ei, row_ptr, fill, csr_src, E);

    gemm128_kernel<<<(N + 31) / 32, 256, 0, stream>>>(hbuf, W0, buf1h, N);
    agg128_kernel<<<N, 128, 0, stream>>>(buf1h, row_ptr, degi, csr_src, dinv, b0, buf2, N, 1);
    gemm128_kernel<<<(N + 31) / 32, 256, 0, stream>>>(buf2, W1, buf1h, N);
    agg128_kernel<<<N, 128, 0, stream>>>(buf1h, row_ptr, degi, csr_src, dinv, b1, buf2, N, 1);
    gemm12_kernel<<<((size_t)N * ODIM + 255) / 256, 256, 0, stream>>>(buf2, W2, buf1h, N);
    agg12_kernel<<<((size_t)N * ODIM + 255) / 256, 256, 0, stream>>>(
        buf1h, row_ptr, degi, csr_src, dinv, b2, out, N);
}

// Round 12
// 1036.598 us; speedup vs baseline: 1.0640x; 1.0640x over previous
//
#include <hip/hip_runtime.h>
#include <hip/hip_bf16.h>

#define TT 12
#define HDIM 128
#define ODIM 12
#define KS0 136        // LDS h-row stride in shorts (272 B) — l0 only
#define TPAD 36        // fp32 GCN gemm LDS pad

typedef short bf16x8 __attribute__((ext_vector_type(8)));
typedef float f32x16 __attribute__((ext_vector_type(16)));
typedef float f32x4  __attribute__((ext_vector_type(4)));

__device__ __forceinline__ float fastrcp(float x) { return __builtin_amdgcn_rcpf(x); }
__device__ __forceinline__ float sigf(float x) { return fastrcp(1.f + __expf(-x)); }
__device__ __forceinline__ float tanh_fast(float x) { return 1.f - 2.f * fastrcp(1.f + __expf(2.f * x)); }
__device__ __forceinline__ unsigned short f2bf(float f) {
    union { float f; unsigned int u; } v; v.f = f;
    unsigned int r = v.u + 0x7FFFu + ((v.u >> 16) & 1u);
    return (unsigned short)(r >> 16);
}

// ---------------- weight pre-pack (unchanged from R10/R11) ----------------
// mat0 (Whh0): 32x32-frag layout, slots 0..127 at offset 0 (for l0)
// mat1 (Wih1) at +65536, mat2 (Whh1) at +131072: 16x16-frag layout
__global__ void pack_kernel(const float* __restrict__ Whh0, const float* __restrict__ Wih1,
                            const float* __restrict__ Whh1, unsigned short* __restrict__ Wpk)
{
    int idx = blockIdx.x * 256 + threadIdx.x;
    if (idx >= 384 * 64) return;
    int lane = idx & 63;
    int slot = idx >> 6;
    int mat = slot >> 7;
    int rem = slot & 127;
    if (mat == 0) {
        int cb = rem >> 3, s = rem & 7;
        int col = cb * 32 + (lane & 31);
#pragma unroll
        for (int j = 0; j < 8; ++j) {
            int k = s * 16 + ((lane >> 5) << 3) + j;
            Wpk[((size_t)(slot * 64 + lane) << 3) + j] = f2bf(Whh0[col * 128 + k]);
        }
    } else {
        const float* src = (mat == 1) ? Wih1 : Whh1;
        int ct = rem >> 2, ks = rem & 3;
        int col = ct * 16 + (lane & 15);
#pragma unroll
        for (int j = 0; j < 8; ++j) {
            int k = ks * 32 + ((lane >> 4) << 3) + j;
            Wpk[((size_t)(slot * 64 + lane) << 3) + j] = f2bf(src[col * 128 + k]);
        }
    }
}

// ---------------- L0: layer-0 LSTM, Whh0 in LDS; COALESCED h0seq stores ----------------
__global__ __launch_bounds__(512, 1) void lstm_l0_kernel(
    const float* __restrict__ x,
    const unsigned short* __restrict__ Wpk,
    const float* __restrict__ Wih0,
    const float* __restrict__ bih0, const float* __restrict__ bhh0,
    unsigned short* __restrict__ h0seq,       // [N][12][128] bf16
    int N, int ntiles)
{
    __shared__ unsigned short wlds[65536];
    __shared__ unsigned short hA0[64 * KS0];
    __shared__ float xls[64 * 24];

    const int tid  = threadIdx.x;
    const int w    = tid >> 6;
    const int ln   = tid & 63;
    const int ln31 = ln & 31;
    const int half = ln >> 5;
    const int wsub = w & 3;
    const int rb   = w >> 2;
    const int col  = wsub * 32 + ln31;
    // cooperative-copy coords: thread handles node cm, channels [cc0, cc0+16)
    const int cm   = tid >> 3;
    const int cc0  = (tid & 7) << 4;

    for (int i = tid * 8; i < 65536; i += 512 * 8)
        *(bf16x8*)(wlds + i) = *(const bf16x8*)(Wpk + i);

    float wx0[4], wx1[4], br0[4];
#pragma unroll
    for (int g = 0; g < 4; ++g) {
        int row = (g << 7) + col;
        wx0[g] = Wih0[row * 2 + 0];
        wx1[g] = Wih0[row * 2 + 1];
        br0[g] = bih0[row] + bhh0[row];
    }

    for (int tile = blockIdx.x; tile < ntiles; tile += gridDim.x) {
        const int nbase = tile * 64;
        __syncthreads();
        for (int i = tid; i < 64 * 24; i += 512) {
            int n = nbase + i / 24;
            xls[i] = (n < N) ? x[nbase * 24 + i] : 0.f;
        }
        for (int i = tid; i < 64 * KS0; i += 512) hA0[i] = 0;
        float c0[16];
#pragma unroll
        for (int r = 0; r < 16; ++r) c0[r] = 0.f;
        __syncthreads();

        const int ncp = nbase + cm;           // copy-row node id
        const bool cok = ncp < N;

        for (int t = 0; t < TT; ++t) {
            f32x16 acc[4];
#pragma unroll
            for (int g = 0; g < 4; ++g)
#pragma unroll
                for (int e = 0; e < 16; ++e) acc[g][e] = 0.f;
#pragma unroll
            for (int s = 0; s < 8; ++s) {
                bf16x8 a = *(const bf16x8*)(hA0 + (rb * 32 + ln31) * KS0 + s * 16 + half * 8);
#pragma unroll
                for (int g = 0; g < 4; ++g) {
                    int cb = g * 4 + wsub;
                    bf16x8 b = *(const bf16x8*)(wlds + (((cb * 8 + s) * 64 + ln) << 3));
                    acc[g] = __builtin_amdgcn_mfma_f32_32x32x16_bf16(a, b, acc[g], 0, 0, 0);
                }
            }
            __syncthreads();                   // B1: hA0 reads done
#pragma unroll
            for (int r = 0; r < 16; ++r) {
                int node = rb * 32 + (r & 3) + 8 * (r >> 2) + 4 * half;
                float xa = xls[node * 24 + t * 2 + 0];
                float xb = xls[node * 24 + t * 2 + 1];
                float zi = acc[0][r] + br0[0] + wx0[0] * xa + wx1[0] * xb;
                float zf = acc[1][r] + br0[1] + wx0[1] * xa + wx1[1] * xb;
                float zg = acc[2][r] + br0[2] + wx0[2] * xa + wx1[2] * xb;
                float zo = acc[3][r] + br0[3] + wx0[3] * xa + wx1[3] * xb;
                float cn = sigf(zf) * c0[r] + sigf(zi) * tanh_fast(zg);
                c0[r] = cn;
                float h = sigf(zo) * tanh_fast(cn);
                hA0[node * KS0 + col] = f2bf(h);   // LDS only
            }
            __syncthreads();                   // B2: h0_t complete in hA0
            // cooperative coalesced store: 2 x 16B per thread (fire-and-forget)
            if (cok) {
                bf16x8 v0 = *(const bf16x8*)(hA0 + cm * KS0 + cc0);
                bf16x8 v1 = *(const bf16x8*)(hA0 + cm * KS0 + cc0 + 8);
                unsigned short* dp = h0seq + ((size_t)ncp * TT + t) * HDIM + cc0;
                *(bf16x8*)(dp)     = v0;
                *(bf16x8*)(dp + 8) = v1;
            }
            // hA0 reads for the copy complete before next B1; next epilogue
            // (which overwrites hA0) happens only after next B1.
        }
    }
}

// ---------------- L1: 16x16x32, dbuf frag-contiguous hA1, 1 barrier/t, NO prefetch ----------------
// hA1 element (m,ch): addr = ((rt*4+ks)*64 + q*16 + l15)*8 + j  (m=rt*16+l15, ch=ks*32+q*8+j)
// GEMM A-read lane ln: ((rt*4+ks)*64 + ln)*8 -> lane-contiguous ds_read_b128, 0 conflicts.
__global__ __launch_bounds__(512) void lstm_l1f_kernel(
    const unsigned short* __restrict__ h0seq, // [N][12][128] bf16
    const unsigned short* __restrict__ Wpk,   // +65536 = Wih1(16), +131072 = Whh1(16)
    const float* __restrict__ bih1, const float* __restrict__ bhh1,
    float* __restrict__ hbuf,                 // [N][128] fp32 out
    int N, int ntiles)
{
    __shared__ unsigned short wlds[65536];    // Whh1, 128 KB
    __shared__ unsigned short hA1[2][8192];   // 2 x 16 KB

    const int tid  = threadIdx.x;
    const int w    = tid >> 6;                // 0..7: ch block
    const int ln   = tid & 63;
    const int l15  = ln & 15;
    const int quad = ln >> 4;
    const int ch   = w * 16 + l15;
    const int chk  = ch >> 5;
    const int chq  = (ch >> 3) & 3;
    const int chj  = ch & 7;

    for (int i = tid * 8; i < 65536; i += 512 * 8)
        *(bf16x8*)(wlds + i) = *(const bf16x8*)(Wpk + 131072 + i);

    // Wih1 fragments -> registers (16 frags = 64 VGPR)
    bf16x8 wfr[4][4];
#pragma unroll
    for (int g = 0; g < 4; ++g)
#pragma unroll
        for (int ks = 0; ks < 4; ++ks) {
            int slot = (g * 8 + w) * 4 + ks;
            wfr[g][ks] = *(const bf16x8*)(Wpk + 65536 + ((size_t)(slot * 64 + ln) << 3));
        }

    float br1[4];
#pragma unroll
    for (int g = 0; g < 4; ++g) {
        int row = (g << 7) + ch;
        br1[g] = bih1[row] + bhh1[row];
    }

    const bf16x8 zv = {0, 0, 0, 0, 0, 0, 0, 0};
    __syncthreads();

    for (int tile = blockIdx.x; tile < ntiles; tile += gridDim.x) {
        __syncthreads();                       // prev tile's buf reads done
        for (int i = tid; i < 1024; i += 512)
            *(bf16x8*)(hA1[0] + i * 8) = zv;
        float c1[16];
#pragma unroll
        for (int r = 0; r < 16; ++r) c1[r] = 0.f;

        int na[4]; bool ok[4];
#pragma unroll
        for (int rt = 0; rt < 4; ++rt) { na[rt] = tile * 64 + rt * 16 + l15; ok[rt] = na[rt] < N; }
        __syncthreads();                       // buf0 zero visible

        for (int t = 0; t < TT; ++t) {
            const unsigned short* usp = hA1[t & 1];
            unsigned short* dst = hA1[(t & 1) ^ 1];

            f32x4 acc[4][4];
#pragma unroll
            for (int rt = 0; rt < 4; ++rt)
#pragma unroll
                for (int g = 0; g < 4; ++g)
#pragma unroll
                    for (int e = 0; e < 4; ++e) acc[rt][g][e] = 0.f;

            // input GEMM: per-ks regular loads (L2/L3-cacheable), consumed immediately
#pragma unroll
            for (int ks = 0; ks < 4; ++ks) {
                bf16x8 a[4];
#pragma unroll
                for (int rt = 0; rt < 4; ++rt)
                    a[rt] = ok[rt]
                        ? *(const bf16x8*)(h0seq + ((size_t)na[rt] * TT + t) * HDIM + ks * 32 + quad * 8)
                        : zv;
#pragma unroll
                for (int g = 0; g < 4; ++g)
#pragma unroll
                    for (int rt = 0; rt < 4; ++rt)
                        acc[rt][g] = __builtin_amdgcn_mfma_f32_16x16x32_bf16(a[rt], wfr[g][ks], acc[rt][g], 0, 0, 0);
            }
            // recurrent GEMM (lane-contiguous LDS reads + wlds)
#pragma unroll
            for (int ks = 0; ks < 4; ++ks) {
                bf16x8 a[4];
#pragma unroll
                for (int rt = 0; rt < 4; ++rt)
                    a[rt] = *(const bf16x8*)(usp + (((rt * 4 + ks) * 64 + ln) << 3));
#pragma unroll
                for (int g = 0; g < 4; ++g) {
                    int slot = (g * 8 + w) * 4 + ks;
                    bf16x8 b = *(const bf16x8*)(wlds + ((size_t)(slot * 64 + ln) << 3));
#pragma unroll
                    for (int rt = 0; rt < 4; ++rt)
                        acc[rt][g] = __builtin_amdgcn_mfma_f32_16x16x32_bf16(a[rt], b, acc[rt][g], 0, 0, 0);
                }
            }

            // epilogue -> other buffer (no pre-barrier needed)
#pragma unroll
            for (int rt = 0; rt < 4; ++rt) {
#pragma unroll
                for (int rg = 0; rg < 4; ++rg) {
                    int ci = rt * 4 + rg;
                    float zi = acc[rt][0][rg] + br1[0];
                    float zf = acc[rt][1][rg] + br1[1];
                    float zg = acc[rt][2][rg] + br1[2];
                    float zo = acc[rt][3][rg] + br1[3];
                    float cn = sigf(zf) * c1[ci] + sigf(zi) * tanh_fast(zg);
                    c1[ci] = cn;
                    float h = sigf(zo) * tanh_fast(cn);
                    if (t + 1 < TT) {
                        dst[(((rt * 4 + chk) * 64 + chq * 16 + quad * 4 + rg) << 3) + chj] = f2bf(h);
                    } else {
                        int n = tile * 64 + rt * 16 + quad * 4 + rg;
                        if (n < N) hbuf[n * HDIM + ch] = h;
                    }
                }
            }
            __syncthreads();                   // single barrier per t
        }
    }
}

// ---------------- GCN: CSR build (unchanged) ----------------
__global__ void deg_count_kernel(const int* __restrict__ ei, int* __restrict__ degi, int E)
{
    int e = blockIdx.x * 256 + threadIdx.x;
    if (e < E) atomicAdd(&degi[ei[E + e]], 1);
}

__global__ void row_alloc_kernel(const int* __restrict__ degi, int* __restrict__ row_ptr,
                                 float* __restrict__ dinv, int* __restrict__ counter, int N)
{
    int n = blockIdx.x * 256 + threadIdx.x;
    int lane = threadIdx.x & 63;
    int v = (n < N) ? degi[n] : 0;
    int incl = v;
    for (int off = 1; off < 64; off <<= 1) {
        int u = __shfl_up(incl, off);
        if (lane >= off) incl += u;
    }
    int base = 0;
    if (lane == 63) base = atomicAdd(counter, incl);
    base = __shfl(base, 63);
    if (n < N) {
        row_ptr[n] = base + (incl - v);
        dinv[n] = rsqrtf((float)(v + 1));
    }
}

__global__ void csr_fill_kernel(const int* __restrict__ ei, const int* __restrict__ row_ptr,
                                int* __restrict__ fill, int* __restrict__ csr_src, int E)
{
    int e = blockIdx.x * 256 + threadIdx.x;
    if (e < E) {
        int d = ei[E + e];
        int p = atomicAdd(&fill[d], 1);
        csr_src[row_ptr[d] + p] = ei[e];
    }
}

// ---------------- GCN: transform + aggregate (fp16 messages; unchanged) ----------------
__global__ __launch_bounds__(256) void gemm128_kernel(const float* __restrict__ X,
                                                      const float* __restrict__ W,
                                                      _Float16* __restrict__ Y, int N)
{
    __shared__ float XT[128 * TPAD];
    const int tid = threadIdx.x;
    const int nbase = blockIdx.x * 32;
    for (int idx = tid; idx < 32 * 128; idx += 256) {
        int m = idx >> 7, k = idx & 127;
        int n = nbase + m;
        XT[k * TPAD + m] = (n < N) ? X[n * HDIM + k] : 0.f;
    }
    __syncthreads();
    const int c  = tid & 63;
    const int mb = (tid >> 6) << 3;
    float acc[8][2];
#pragma unroll
    for (int i = 0; i < 8; ++i) { acc[i][0] = 0.f; acc[i][1] = 0.f; }
    for (int k = 0; k < 128; ++k) {
        const float* xr = &XT[k * TPAD + mb];
        float4 a0 = *(const float4*)(xr);
        float4 a1 = *(const float4*)(xr + 4);
        float a[8] = {a0.x, a0.y, a0.z, a0.w, a1.x, a1.y, a1.z, a1.w};
        float b0 = W[k * HDIM + c];
        float b1 = W[k * HDIM + c + 64];
#pragma unroll
        for (int i = 0; i < 8; ++i) {
            acc[i][0] = fmaf(a[i], b0, acc[i][0]);
            acc[i][1] = fmaf(a[i], b1, acc[i][1]);
        }
    }
#pragma unroll
    for (int i = 0; i < 8; ++i) {
        int n = nbase + mb + i;
        if (n < N) {
            Y[n * HDIM + c]      = (_Float16)acc[i][0];
            Y[n * HDIM + c + 64] = (_Float16)acc[i][1];
        }
    }
}

__global__ void gemm12_kernel(const float* __restrict__ X, const float* __restrict__ W2,
                              _Float16* __restrict__ Y, int N)
{
    int idx = blockIdx.x * 256 + threadIdx.x;
    int n = idx / ODIM, c = idx - n * ODIM;
    if (n >= N) return;
    float acc = 0.f;
    for (int k = 0; k < 128; ++k) acc = fmaf(X[n * HDIM + k], W2[k * ODIM + c], acc);
    Y[n * ODIM + c] = (_Float16)acc;
}

__global__ __launch_bounds__(128) void agg128_kernel(const _Float16* __restrict__ hW,
        const int* __restrict__ row_ptr, const int* __restrict__ degi,
        const int* __restrict__ csr_src, const float* __restrict__ dinv,
        const float* __restrict__ bias, float* __restrict__ out, int N, int do_relu)
{
    int n = blockIdx.x;
    int c = threadIdx.x;
    float dn = dinv[n];
    float acc = (float)hW[n * HDIM + c] * dn * dn;
    int start = row_ptr[n];
    int cnt = degi[n];
    for (int i = 0; i < cnt; ++i) {
        int s = csr_src[start + i];
        acc = fmaf((float)hW[s * HDIM + c], dinv[s] * dn, acc);
    }
    float v = acc + bias[c];
    if (do_relu) v = fmaxf(v, 0.f);
    out[n * HDIM + c] = v;
}

__global__ void agg12_kernel(const _Float16* __restrict__ hW, const int* __restrict__ row_ptr,
        const int* __restrict__ degi, const int* __restrict__ csr_src,
        const float* __restrict__ dinv, const float* __restrict__ b2,
        float* __restrict__ out, int N)
{
    int idx = blockIdx.x * 256 + threadIdx.x;
    int n = idx / ODIM, c = idx - n * ODIM;
    if (n >= N) return;
    float dn = dinv[n];
    float acc = (float)hW[n * ODIM + c] * dn * dn;
    int start = row_ptr[n], cnt = degi[n];
    for (int i = 0; i < cnt; ++i) {
        int s = csr_src[start + i];
        acc = fmaf((float)hW[s * ODIM + c], dinv[s] * dn, acc);
    }
    out[n * ODIM + c] = acc + b2[c];
}

extern "C" void kernel_launch(void* const* d_in, const int* in_sizes, int n_in,
                              void* d_out, int out_size, void* d_ws, size_t ws_size,
                              hipStream_t stream)
{
    const float* x     = (const float*)d_in[0];
    const int*   ei    = (const int*)d_in[1];
    const float* Wih0  = (const float*)d_in[2];
    const float* Whh0  = (const float*)d_in[3];
    const float* bih0  = (const float*)d_in[4];
    const float* bhh0  = (const float*)d_in[5];
    const float* Wih1  = (const float*)d_in[6];
    const float* Whh1  = (const float*)d_in[7];
    const float* bih1  = (const float*)d_in[8];
    const float* bhh1  = (const float*)d_in[9];
    const float* W0    = (const float*)d_in[10];
    const float* b0    = (const float*)d_in[11];
    const float* W1    = (const float*)d_in[12];
    const float* b1    = (const float*)d_in[13];
    const float* W2    = (const float*)d_in[14];
    const float* b2    = (const float*)d_in[15];
    float* out = (float*)d_out;

    const int N = in_sizes[0] / (TT * 2);
    const int E = in_sizes[1] / 2;

    // ---- workspace layout ----
    unsigned short* Wpk = (unsigned short*)d_ws;          // 384 KB
    float* fbase = (float*)((char*)d_ws + 393216);
    float* hbuf = fbase;                                  // N*128 fp32
    float* buf1 = hbuf + (size_t)N * HDIM;                // N*128 (fp16 messages)
    float* buf2 = buf1 + (size_t)N * HDIM;                // N*128 fp32
    float* dinv = buf2 + (size_t)N * HDIM;                // N
    int* degi    = (int*)(dinv + N);                      // N
    int* fill    = degi + N;                              // N
    int* counter = fill + N;                              // 1
    int* row_ptr = counter + 1;                           // N
    int* csr_src = row_ptr + N;                           // E
    size_t h0_off = (((size_t)((char*)(csr_src + E) - (char*)d_ws)) + 255) & ~(size_t)255;
    unsigned short* h0seq = (unsigned short*)((char*)d_ws + h0_off);   // N*12*128 bf16
    _Float16* buf1h = (_Float16*)buf1;

    hipMemsetAsync(degi, 0, (size_t)(2 * N + 1) * sizeof(int), stream);

    pack_kernel<<<(384 * 64 + 255) / 256, 256, 0, stream>>>(Whh0, Wih1, Whh1, Wpk);

    const int ntiles = (N + 63) / 64;
    lstm_l0_kernel<<<256, 512, 0, stream>>>(x, Wpk, Wih0, bih0, bhh0, h0seq, N, ntiles);
    lstm_l1f_kernel<<<256, 512, 0, stream>>>(h0seq, Wpk, bih1, bhh1, hbuf, N, ntiles);

    deg_count_kernel<<<(E + 255) / 256, 256, 0, stream>>>(ei, degi, E);
    row_alloc_kernel<<<(N + 255) / 256, 256, 0, stream>>>(degi, row_ptr, dinv, counter, N);
    csr_fill_kernel<<<(E + 255) / 256, 256, 0, stream>>>(ei, row_ptr, fill, csr_src, E);

    gemm128_kernel<<<(N + 31) / 32, 256, 0, stream>>>(hbuf, W0, buf1h, N);
    agg128_kernel<<<N, 128, 0, stream>>>(buf1h, row_ptr, degi, csr_src, dinv, b0, buf2, N, 1);
    gemm128_kernel<<<(N + 31) / 32, 256, 0, stream>>>(buf2, W1, buf1h, N);
    agg128_kernel<<<N, 128, 0, stream>>>(buf1h, row_ptr, degi, csr_src, dinv, b1, buf2, N, 1);
    gemm12_kernel<<<((size_t)N * ODIM + 255) / 256, 256, 0, stream>>>(buf2, W2, buf1h, N);
    agg12_kernel<<<((size_t)N * ODIM + 255) / 256, 256, 0, stream>>>(
        buf1h, row_ptr, degi, csr_src, dinv, b2, out, N);
}

// Round 13
// 940.162 us; speedup vs baseline: 1.1731x; 1.1026x over previous
//
#include <hip/hip_runtime.h>
#include <hip/hip_bf16.h>

#define TT 12
#define HDIM 128
#define ODIM 12
#define KS0 136        // LDS h-row stride in shorts (272 B) — l0 only
#define TPAD 36        // fp32 GCN gemm LDS pad

typedef short bf16x8 __attribute__((ext_vector_type(8)));
typedef float f32x16 __attribute__((ext_vector_type(16)));
typedef float f32x4  __attribute__((ext_vector_type(4)));

__device__ __forceinline__ float fastrcp(float x) { return __builtin_amdgcn_rcpf(x); }
__device__ __forceinline__ float sigf(float x) { return fastrcp(1.f + __expf(-x)); }
__device__ __forceinline__ float tanh_fast(float x) { return 1.f - 2.f * fastrcp(1.f + __expf(2.f * x)); }
__device__ __forceinline__ unsigned short f2bf(float f) {
    union { float f; unsigned int u; } v; v.f = f;
    unsigned int r = v.u + 0x7FFFu + ((v.u >> 16) & 1u);
    return (unsigned short)(r >> 16);
}

// ---------------- weight pre-pack (unchanged) ----------------
// mat0 (Whh0): 32x32-frag layout, slots 0..127. mat1 (Wih1) +65536, mat2 (Whh1) +131072: 16x16-frag.
__global__ void pack_kernel(const float* __restrict__ Whh0, const float* __restrict__ Wih1,
                            const float* __restrict__ Whh1, unsigned short* __restrict__ Wpk)
{
    int idx = blockIdx.x * 256 + threadIdx.x;
    if (idx >= 384 * 64) return;
    int lane = idx & 63;
    int slot = idx >> 6;
    int mat = slot >> 7;
    int rem = slot & 127;
    if (mat == 0) {
        int cb = rem >> 3, s = rem & 7;
        int col = cb * 32 + (lane & 31);
#pragma unroll
        for (int j = 0; j < 8; ++j) {
            int k = s * 16 + ((lane >> 5) << 3) + j;
            Wpk[((size_t)(slot * 64 + lane) << 3) + j] = f2bf(Whh0[col * 128 + k]);
        }
    } else {
        const float* src = (mat == 1) ? Wih1 : Whh1;
        int ct = rem >> 2, ks = rem & 3;
        int col = ct * 16 + (lane & 15);
#pragma unroll
        for (int j = 0; j < 8; ++j) {
            int k = ks * 32 + ((lane >> 4) << 3) + j;
            Wpk[((size_t)(slot * 64 + lane) << 3) + j] = f2bf(src[col * 128 + k]);
        }
    }
}

// ---------------- L0: layer-0 LSTM; h0 emitted in l1 A-FRAGMENT order ----------------
// h0f[(tile*12+t)*8192 + frag*8 + j], frag = (rt*4+ks)*64 + q*16 + l15
//   -> element (m = rt*16+l15, ch = ks*32+q*8+j) of the 64-node tile.
__global__ __launch_bounds__(512, 1) void lstm_l0_kernel(
    const float* __restrict__ x,
    const unsigned short* __restrict__ Wpk,
    const float* __restrict__ Wih0,
    const float* __restrict__ bih0, const float* __restrict__ bhh0,
    unsigned short* __restrict__ h0f,         // [ntiles][12][8192] bf16 (frag order)
    int N, int ntiles)
{
    __shared__ unsigned short wlds[65536];
    __shared__ unsigned short hA0[64 * KS0];
    __shared__ float xls[64 * 24];

    const int tid  = threadIdx.x;
    const int w    = tid >> 6;
    const int ln   = tid & 63;
    const int ln31 = ln & 31;
    const int half = ln >> 5;
    const int wsub = w & 3;
    const int rb   = w >> 2;
    const int col  = wsub * 32 + ln31;

    for (int i = tid * 8; i < 65536; i += 512 * 8)
        *(bf16x8*)(wlds + i) = *(const bf16x8*)(Wpk + i);

    float wx0[4], wx1[4], br0[4];
#pragma unroll
    for (int g = 0; g < 4; ++g) {
        int row = (g << 7) + col;
        wx0[g] = Wih0[row * 2 + 0];
        wx1[g] = Wih0[row * 2 + 1];
        br0[g] = bih0[row] + bhh0[row];
    }

    for (int tile = blockIdx.x; tile < ntiles; tile += gridDim.x) {
        const int nbase = tile * 64;
        __syncthreads();
        for (int i = tid; i < 64 * 24; i += 512) {
            int n = nbase + i / 24;
            xls[i] = (n < N) ? x[nbase * 24 + i] : 0.f;
        }
        for (int i = tid; i < 64 * KS0; i += 512) hA0[i] = 0;
        float c0[16];
#pragma unroll
        for (int r = 0; r < 16; ++r) c0[r] = 0.f;
        __syncthreads();

        for (int t = 0; t < TT; ++t) {
            f32x16 acc[4];
#pragma unroll
            for (int g = 0; g < 4; ++g)
#pragma unroll
                for (int e = 0; e < 16; ++e) acc[g][e] = 0.f;
#pragma unroll
            for (int s = 0; s < 8; ++s) {
                bf16x8 a = *(const bf16x8*)(hA0 + (rb * 32 + ln31) * KS0 + s * 16 + half * 8);
#pragma unroll
                for (int g = 0; g < 4; ++g) {
                    int cb = g * 4 + wsub;
                    bf16x8 b = *(const bf16x8*)(wlds + (((cb * 8 + s) * 64 + ln) << 3));
                    acc[g] = __builtin_amdgcn_mfma_f32_32x32x16_bf16(a, b, acc[g], 0, 0, 0);
                }
            }
            __syncthreads();                   // B1: hA0 reads done
#pragma unroll
            for (int r = 0; r < 16; ++r) {
                int node = rb * 32 + (r & 3) + 8 * (r >> 2) + 4 * half;
                float xa = xls[node * 24 + t * 2 + 0];
                float xb = xls[node * 24 + t * 2 + 1];
                float zi = acc[0][r] + br0[0] + wx0[0] * xa + wx1[0] * xb;
                float zf = acc[1][r] + br0[1] + wx0[1] * xa + wx1[1] * xb;
                float zg = acc[2][r] + br0[2] + wx0[2] * xa + wx1[2] * xb;
                float zo = acc[3][r] + br0[3] + wx0[3] * xa + wx1[3] * xb;
                float cn = sigf(zf) * c0[r] + sigf(zi) * tanh_fast(zg);
                c0[r] = cn;
                float h = sigf(zo) * tanh_fast(cn);
                hA0[node * KS0 + col] = f2bf(h);   // LDS only
            }
            __syncthreads();                   // B2: h0_t complete in hA0
            // frag-order cooperative copy: dest thread-linear 16B (fully coalesced)
            {
                unsigned short* dt = h0f + (((size_t)(tile * TT + t)) << 13);
#pragma unroll
                for (int it = 0; it < 2; ++it) {
                    int i = tid + it * 512;            // frag id 0..1023
                    int rtks = i >> 6;                 // rt*4+ks
                    int lane = i & 63;
                    int m   = ((rtks >> 2) << 4) + (lane & 15);
                    int chb = ((rtks & 3) << 5) + ((lane >> 4) << 3);
                    bf16x8 v = *(const bf16x8*)(hA0 + m * KS0 + chb);
                    *(bf16x8*)(dt + ((size_t)i << 3)) = v;
                }
            }
        }
    }
}

// ---------------- L1: 16x16x32, dbuf hA1, 1 barrier/t, COALESCED frag A-loads ----------------
__global__ __launch_bounds__(512) void lstm_l1f_kernel(
    const unsigned short* __restrict__ h0f,   // frag-order h0 tiles
    const unsigned short* __restrict__ Wpk,   // +65536 = Wih1(16), +131072 = Whh1(16)
    const float* __restrict__ bih1, const float* __restrict__ bhh1,
    float* __restrict__ hbuf,                 // [N][128] fp32 out
    int N, int ntiles)
{
    __shared__ unsigned short wlds[65536];    // Whh1, 128 KB
    __shared__ unsigned short hA1[2][8192];   // 2 x 16 KB

    const int tid  = threadIdx.x;
    const int w    = tid >> 6;                // 0..7: ch block
    const int ln   = tid & 63;
    const int l15  = ln & 15;
    const int quad = ln >> 4;
    const int ch   = w * 16 + l15;
    const int chk  = ch >> 5;
    const int chq  = (ch >> 3) & 3;
    const int chj  = ch & 7;

    for (int i = tid * 8; i < 65536; i += 512 * 8)
        *(bf16x8*)(wlds + i) = *(const bf16x8*)(Wpk + 131072 + i);

    bf16x8 wfr[4][4];
#pragma unroll
    for (int g = 0; g < 4; ++g)
#pragma unroll
        for (int ks = 0; ks < 4; ++ks) {
            int slot = (g * 8 + w) * 4 + ks;
            wfr[g][ks] = *(const bf16x8*)(Wpk + 65536 + ((size_t)(slot * 64 + ln) << 3));
        }

    float br1[4];
#pragma unroll
    for (int g = 0; g < 4; ++g) {
        int row = (g << 7) + ch;
        br1[g] = bih1[row] + bhh1[row];
    }

    const bf16x8 zv = {0, 0, 0, 0, 0, 0, 0, 0};
    __syncthreads();

    for (int tile = blockIdx.x; tile < ntiles; tile += gridDim.x) {
        __syncthreads();                       // prev tile's buf reads done
        for (int i = tid; i < 1024; i += 512)
            *(bf16x8*)(hA1[0] + i * 8) = zv;
        float c1[16];
#pragma unroll
        for (int r = 0; r < 16; ++r) c1[r] = 0.f;
        __syncthreads();                       // buf0 zero visible

        for (int t = 0; t < TT; ++t) {
            const unsigned short* usp = hA1[t & 1];
            unsigned short* dst = hA1[(t & 1) ^ 1];
            const unsigned short* h0t = h0f + (((size_t)(tile * TT + t)) << 13);

            f32x4 acc[4][4];
#pragma unroll
            for (int rt = 0; rt < 4; ++rt)
#pragma unroll
                for (int g = 0; g < 4; ++g)
#pragma unroll
                    for (int e = 0; e < 4; ++e) acc[rt][g][e] = 0.f;

            // per-ks: issue coalesced global A-loads, hide behind recurrent MFMAs, then input MFMAs
#pragma unroll
            for (int ks = 0; ks < 4; ++ks) {
                bf16x8 a0[4];
#pragma unroll
                for (int rt = 0; rt < 4; ++rt)
                    a0[rt] = *(const bf16x8*)(h0t + (((rt * 4 + ks) * 64 + ln) << 3));  // 1KB/wave contiguous
                bf16x8 a1[4];
#pragma unroll
                for (int rt = 0; rt < 4; ++rt)
                    a1[rt] = *(const bf16x8*)(usp + (((rt * 4 + ks) * 64 + ln) << 3));
#pragma unroll
                for (int g = 0; g < 4; ++g) {
                    int slot = (g * 8 + w) * 4 + ks;
                    bf16x8 b = *(const bf16x8*)(wlds + ((size_t)(slot * 64 + ln) << 3));
#pragma unroll
                    for (int rt = 0; rt < 4; ++rt)
                        acc[rt][g] = __builtin_amdgcn_mfma_f32_16x16x32_bf16(a1[rt], b, acc[rt][g], 0, 0, 0);
                }
#pragma unroll
                for (int g = 0; g < 4; ++g)
#pragma unroll
                    for (int rt = 0; rt < 4; ++rt)
                        acc[rt][g] = __builtin_amdgcn_mfma_f32_16x16x32_bf16(a0[rt], wfr[g][ks], acc[rt][g], 0, 0, 0);
            }

            // epilogue -> other buffer
#pragma unroll
            for (int rt = 0; rt < 4; ++rt) {
#pragma unroll
                for (int rg = 0; rg < 4; ++rg) {
                    int ci = rt * 4 + rg;
                    float zi = acc[rt][0][rg] + br1[0];
                    float zf = acc[rt][1][rg] + br1[1];
                    float zg = acc[rt][2][rg] + br1[2];
                    float zo = acc[rt][3][rg] + br1[3];
                    float cn = sigf(zf) * c1[ci] + sigf(zi) * tanh_fast(zg);
                    c1[ci] = cn;
                    float h = sigf(zo) * tanh_fast(cn);
                    if (t + 1 < TT) {
                        dst[(((rt * 4 + chk) * 64 + chq * 16 + quad * 4 + rg) << 3) + chj] = f2bf(h);
                    } else {
                        int n = tile * 64 + rt * 16 + quad * 4 + rg;
                        if (n < N) hbuf[n * HDIM + ch] = h;
                    }
                }
            }
            __syncthreads();                   // single barrier per t
        }
    }
}

// ---------------- GCN: CSR build (unchanged) ----------------
__global__ void deg_count_kernel(const int* __restrict__ ei, int* __restrict__ degi, int E)
{
    int e = blockIdx.x * 256 + threadIdx.x;
    if (e < E) atomicAdd(&degi[ei[E + e]], 1);
}

__global__ void row_alloc_kernel(const int* __restrict__ degi, int* __restrict__ row_ptr,
                                 float* __restrict__ dinv, int* __restrict__ counter, int N)
{
    int n = blockIdx.x * 256 + threadIdx.x;
    int lane = threadIdx.x & 63;
    int v = (n < N) ? degi[n] : 0;
    int incl = v;
    for (int off = 1; off < 64; off <<= 1) {
        int u = __shfl_up(incl, off);
        if (lane >= off) incl += u;
    }
    int base = 0;
    if (lane == 63) base = atomicAdd(counter, incl);
    base = __shfl(base, 63);
    if (n < N) {
        row_ptr[n] = base + (incl - v);
        dinv[n] = rsqrtf((float)(v + 1));
    }
}

__global__ void csr_fill_kernel(const int* __restrict__ ei, const int* __restrict__ row_ptr,
                                int* __restrict__ fill, int* __restrict__ csr_src, int E)
{
    int e = blockIdx.x * 256 + threadIdx.x;
    if (e < E) {
        int d = ei[E + e];
        int p = atomicAdd(&fill[d], 1);
        csr_src[row_ptr[d] + p] = ei[e];
    }
}

// ---------------- GCN: transform + aggregate (fp16 messages; unchanged) ----------------
__global__ __launch_bounds__(256) void gemm128_kernel(const float* __restrict__ X,
                                                      const float* __restrict__ W,
                                                      _Float16* __restrict__ Y, int N)
{
    __shared__ float XT[128 * TPAD];
    const int tid = threadIdx.x;
    const int nbase = blockIdx.x * 32;
    for (int idx = tid; idx < 32 * 128; idx += 256) {
        int m = idx >> 7, k = idx & 127;
        int n = nbase + m;
        XT[k * TPAD + m] = (n < N) ? X[n * HDIM + k] : 0.f;
    }
    __syncthreads();
    const int c  = tid & 63;
    const int mb = (tid >> 6) << 3;
    float acc[8][2];
#pragma unroll
    for (int i = 0; i < 8; ++i) { acc[i][0] = 0.f; acc[i][1] = 0.f; }
    for (int k = 0; k < 128; ++k) {
        const float* xr = &XT[k * TPAD + mb];
        float4 a0 = *(const float4*)(xr);
        float4 a1 = *(const float4*)(xr + 4);
        float a[8] = {a0.x, a0.y, a0.z, a0.w, a1.x, a1.y, a1.z, a1.w};
        float b0 = W[k * HDIM + c];
        float b1 = W[k * HDIM + c + 64];
#pragma unroll
        for (int i = 0; i < 8; ++i) {
            acc[i][0] = fmaf(a[i], b0, acc[i][0]);
            acc[i][1] = fmaf(a[i], b1, acc[i][1]);
        }
    }
#pragma unroll
    for (int i = 0; i < 8; ++i) {
        int n = nbase + mb + i;
        if (n < N) {
            Y[n * HDIM + c]      = (_Float16)acc[i][0];
            Y[n * HDIM + c + 64] = (_Float16)acc[i][1];
        }
    }
}

__global__ void gemm12_kernel(const float* __restrict__ X, const float* __restrict__ W2,
                              _Float16* __restrict__ Y, int N)
{
    int idx = blockIdx.x * 256 + threadIdx.x;
    int n = idx / ODIM, c = idx - n * ODIM;
    if (n >= N) return;
    float acc = 0.f;
    for (int k = 0; k < 128; ++k) acc = fmaf(X[n * HDIM + k], W2[k * ODIM + c], acc);
    Y[n * ODIM + c] = (_Float16)acc;
}

__global__ __launch_bounds__(128) void agg128_kernel(const _Float16* __restrict__ hW,
        const int* __restrict__ row_ptr, const int* __restrict__ degi,
        const int* __restrict__ csr_src, const float* __restrict__ dinv,
        const float* __restrict__ bias, float* __restrict__ out, int N, int do_relu)
{
    int n = blockIdx.x;
    int c = threadIdx.x;
    float dn = dinv[n];
    float acc = (float)hW[n * HDIM + c] * dn * dn;
    int start = row_ptr[n];
    int cnt = degi[n];
    for (int i = 0; i < cnt; ++i) {
        int s = csr_src[start + i];
        acc = fmaf((float)hW[s * HDIM + c], dinv[s] * dn, acc);
    }
    float v = acc + bias[c];
    if (do_relu) v = fmaxf(v, 0.f);
    out[n * HDIM + c] = v;
}

__global__ void agg12_kernel(const _Float16* __restrict__ hW, const int* __restrict__ row_ptr,
        const int* __restrict__ degi, const int* __restrict__ csr_src,
        const float* __restrict__ dinv, const float* __restrict__ b2,
        float* __restrict__ out, int N)
{
    int idx = blockIdx.x * 256 + threadIdx.x;
    int n = idx / ODIM, c = idx - n * ODIM;
    if (n >= N) return;
    float dn = dinv[n];
    float acc = (float)hW[n * ODIM + c] * dn * dn;
    int start = row_ptr[n], cnt = degi[n];
    for (int i = 0; i < cnt; ++i) {
        int s = csr_src[start + i];
        acc = fmaf((float)hW[s * ODIM + c], dinv[s] * dn, acc);
    }
    out[n * ODIM + c] = acc + b2[c];
}

extern "C" void kernel_launch(void* const* d_in, const int* in_sizes, int n_in,
                              void* d_out, int out_size, void* d_ws, size_t ws_size,
                              hipStream_t stream)
{
    const float* x     = (const float*)d_in[0];
    const int*   ei    = (const int*)d_in[1];
    const float* Wih0  = (const float*)d_in[2];
    const float* Whh0  = (const float*)d_in[3];
    const float* bih0  = (const float*)d_in[4];
    const float* bhh0  = (const float*)d_in[5];
    const float* Wih1  = (const float*)d_in[6];
    const float* Whh1  = (const float*)d_in[7];
    const float* bih1  = (const float*)d_in[8];
    const float* bhh1  = (const float*)d_in[9];
    const float* W0    = (const float*)d_in[10];
    const float* b0    = (const float*)d_in[11];
    const float* W1    = (const float*)d_in[12];
    const float* b1    = (const float*)d_in[13];
    const float* W2    = (const float*)d_in[14];
    const float* b2    = (const float*)d_in[15];
    float* out = (float*)d_out;

    const int N = in_sizes[0] / (TT * 2);
    const int E = in_sizes[1] / 2;
    const int ntiles = (N + 63) / 64;

    // ---- workspace layout ----
    unsigned short* Wpk = (unsigned short*)d_ws;          // 384 KB
    float* fbase = (float*)((char*)d_ws + 393216);
    float* hbuf = fbase;                                  // N*128 fp32
    float* buf1 = hbuf + (size_t)N * HDIM;                // N*128 (fp16 messages)
    float* buf2 = buf1 + (size_t)N * HDIM;                // N*128 fp32
    float* dinv = buf2 + (size_t)N * HDIM;                // N
    int* degi    = (int*)(dinv + N);                      // N
    int* fill    = degi + N;                              // N
    int* counter = fill + N;                              // 1
    int* row_ptr = counter + 1;                           // N
    int* csr_src = row_ptr + N;                           // E
    size_t h0_off = (((size_t)((char*)(csr_src + E) - (char*)d_ws)) + 255) & ~(size_t)255;
    unsigned short* h0f = (unsigned short*)((char*)d_ws + h0_off);   // ntiles*12*8192 bf16 (~154 MB)
    _Float16* buf1h = (_Float16*)buf1;

    hipMemsetAsync(degi, 0, (size_t)(2 * N + 1) * sizeof(int), stream);

    pack_kernel<<<(384 * 64 + 255) / 256, 256, 0, stream>>>(Whh0, Wih1, Whh1, Wpk);

    lstm_l0_kernel<<<256, 512, 0, stream>>>(x, Wpk, Wih0, bih0, bhh0, h0f, N, ntiles);
    lstm_l1f_kernel<<<256, 512, 0, stream>>>(h0f, Wpk, bih1, bhh1, hbuf, N, ntiles);

    deg_count_kernel<<<(E + 255) / 256, 256, 0, stream>>>(ei, degi, E);
    row_alloc_kernel<<<(N + 255) / 256, 256, 0, stream>>>(degi, row_ptr, dinv, counter, N);
    csr_fill_kernel<<<(E + 255) / 256, 256, 0, stream>>>(ei, row_ptr, fill, csr_src, E);

    gemm128_kernel<<<(N + 31) / 32, 256, 0, stream>>>(hbuf, W0, buf1h, N);
    agg128_kernel<<<N, 128, 0, stream>>>(buf1h, row_ptr, degi, csr_src, dinv, b0, buf2, N, 1);
    gemm128_kernel<<<(N + 31) / 32, 256, 0, stream>>>(buf2, W1, buf1h, N);
    agg128_kernel<<<N, 128, 0, stream>>>(buf1h, row_ptr, degi, csr_src, dinv, b1, buf2, N, 1);
    gemm12_kernel<<<((size_t)N * ODIM + 255) / 256, 256, 0, stream>>>(buf2, W2, buf1h, N);
    agg12_kernel<<<((size_t)N * ODIM + 255) / 256, 256, 0, stream>>>(
        buf1h, row_ptr, degi, csr_src, dinv, b2, out, N);
}